// Round 12
// baseline (106.380 us; speedup 1.0000x reference)
//
#include <hip/hip_runtime.h>

#define Bn    8
#define Cn    64
#define Hn    128
#define Wn    128
#define KK    9
#define OffC  18
#define NG    4
#define Cg    16
#define HW    (Hn*Wn)

#define OFFS_ELEMS (Bn*OffC*HW)
#define WAO_ELEMS  (KK*4*64*8)
#define WAD_ELEMS  (NG*KK*64*8)

// deform tile geometry: 4 output rows, halo 2 up / 2 down (proven)
#define ROWS  4
#define TR    8
#define NW    8
#define TSTR  132

typedef __attribute__((ext_vector_type(8)))  short short8v;
typedef __attribute__((ext_vector_type(4)))  unsigned int uint4v;
typedef __attribute__((ext_vector_type(2)))  float f32x2;
typedef __attribute__((ext_vector_type(16))) float f32x16;

__device__ __forceinline__ unsigned int rne16(float f) {
    unsigned int u = __float_as_uint(f);
    return (u + 0x7FFFu + ((u >> 16) & 1u)) >> 16;   // bf16 RNE
}
// packed bf16 convert: one v_cvt_pk_bf16_f32 (RNE, HW-verified)
__device__ __forceinline__ unsigned int pk2(float lo, float hi) {
    unsigned int w;
    asm("v_cvt_pk_bf16_f32 %0, %1, %2" : "=v"(w) : "v"(lo), "v"(hi));
    return w;
}

// ---------- Kernel 0: prep MFMA A-fragment tables (both convs) ----------
__global__ __launch_bounds__(256) void prep_w_kernel(
    const float* __restrict__ offw, const float* __restrict__ dw,
    unsigned short* __restrict__ wAo, unsigned short* __restrict__ wAd)
{
    const int tid = blockIdx.x * 256 + threadIdx.x;
    const int nth = gridDim.x * 256;
    for (int i = tid; i < WAO_ELEMS; i += nth) {
        const int e    = i & 7;
        const int lane = (i >> 3) & 63;
        const int q    = (i >> 9) & 3;
        const int t    = i >> 11;
        const int o    = lane & 31;
        const int c    = q * 16 + 8 * (lane >> 5) + e;
        const float v  = (o < OffC) ? offw[(o * Cn + c) * KK + t] : 0.f;
        wAo[i] = (unsigned short)rne16(v);
    }
    for (int i = tid; i < WAD_ELEMS; i += nth) {
        const int e    = i & 7;
        const int lane = (i >> 3) & 63;
        const int t    = (i >> 9) % KK;
        const int g    = i / (512 * KK);
        const int o    = lane & 31;
        const int c    = 8 * (lane >> 5) + e;
        const float v  = (o < Cg) ? dw[((g * Cg + o) * Cg + c) * KK + t] : 0.f;
        wAd[i] = (unsigned short)rne16(v);
    }
}

// ---------- Kernel 1: offset conv via MFMA (round-9 proven; pack2 -> pk2) ----------
__global__ __launch_bounds__(256, 4) void offset_conv_kernel(
    const float* __restrict__ x, const unsigned short* __restrict__ wAo,
    const float* __restrict__ bias, float* __restrict__ offs)
{
    const int tid  = threadIdx.x;
    const int wv   = tid >> 6;
    const int lane = tid & 63;
    const int p    = lane & 31;
    const int h    = lane >> 5;
    const int b    = blockIdx.y;
    const int r    = blockIdx.x;
    const int col  = wv * 32 + p;

    const float* xb = x + (size_t)b * Cn * HW;

    f32x16 acc;
#pragma unroll
    for (int i = 0; i < 16; ++i) acc[i] = 0.f;

#pragma unroll 1
    for (int q = 0; q < 4; ++q) {
        unsigned int win[4][3][3];
#pragma unroll
        for (int i = 0; i < 4; ++i) {
            const float* xc0 = xb + (size_t)(q * 16 + 8 * h + 2 * i) * HW;
            const float* xc1 = xc0 + HW;
#pragma unroll
            for (int ky = 0; ky < 3; ++ky) {
                const int  y   = r - 1 + ky;
                const bool yok = ((unsigned)y < (unsigned)Hn);
#pragma unroll
                for (int kx = 0; kx < 3; ++kx) {
                    const int  xx = col - 1 + kx;
                    const bool ok = yok && ((unsigned)xx < (unsigned)Wn);
                    const float f0 = ok ? xc0[y * Wn + xx] : 0.f;
                    const float f1 = ok ? xc1[y * Wn + xx] : 0.f;
                    win[i][ky][kx] = pk2(f0, f1);
                }
            }
        }
#pragma unroll
        for (int t = 0; t < KK; ++t) {
            uint4v bw;
            bw[0] = win[0][t / 3][t % 3];
            bw[1] = win[1][t / 3][t % 3];
            bw[2] = win[2][t / 3][t % 3];
            bw[3] = win[3][t / 3][t % 3];
            const short8v bfrag = __builtin_bit_cast(short8v, bw);
            const short8v afrag = *(const short8v*)(wAo + (size_t)(t * 4 + q) * 512 + lane * 8);
            acc = __builtin_amdgcn_mfma_f32_32x32x16_bf16(afrag, bfrag, acc, 0, 0, 0);
        }
    }

    float* ob = offs + ((size_t)b * OffC * Hn + r) * Wn + col;
#pragma unroll
    for (int reg = 0; reg < 16; ++reg) {
        const int o = (reg & 3) + 8 * (reg >> 2) + 4 * h;
        if (o < OffC) ob[(size_t)o * HW] = acc[reg] + bias[o];
    }
}

// ---------- helper: per-chunk tap state ----------
struct TapS {
    int   t0, t1;          // LDS row offsets (word units)
    int   ia0, ia1, ia2, ia3;
    float m0, m1, m2, m3;
    bool  cond;
    int   x0c, x1c;
};

__device__ __forceinline__ TapS tap_setup(
    int r, int col, int ky, int kx, float offy, float offx, int ylo, int yhi)
{
    TapS s;
    const float pyf = (float)(r - 1 + ky) + offy;
    const float pxf = (float)(col - 1 + kx) + offx;
    const float y0f = floorf(pyf), x0f = floorf(pxf);
    const float wy = pyf - y0f, wx = pxf - x0f;
    const int y0 = (int)y0f, x0 = (int)x0f, y1 = y0 + 1, x1 = x0 + 1;
    const bool vy0 = ((unsigned)y0 < (unsigned)Hn), vy1 = ((unsigned)y1 < (unsigned)Hn);
    const bool vx0 = ((unsigned)x0 < (unsigned)Wn), vx1 = ((unsigned)x1 < (unsigned)Wn);
    const int y0c = min(max(y0, 0), Hn - 1), y1c = min(max(y1, 0), Hn - 1);
    s.x0c = min(max(x0, 0), Wn - 1); s.x1c = min(max(x1, 0), Wn - 1);
    s.m0 = (1.f - wy) * (1.f - wx) * ((vy0 && vx0) ? 1.f : 0.f);
    s.m1 = (1.f - wy) * wx         * ((vy0 && vx1) ? 1.f : 0.f);
    s.m2 = wy * (1.f - wx)         * ((vy1 && vx0) ? 1.f : 0.f);
    s.m3 = wy * wx                 * ((vy1 && vx1) ? 1.f : 0.f);
    s.ia0 = y0c * Wn + s.x0c; s.ia1 = y0c * Wn + s.x1c;
    s.ia2 = y1c * Wn + s.x0c; s.ia3 = y1c * Wn + s.x1c;
    s.cond = (y0c >= ylo) && (y1c <= yhi);
    s.t0 = (y0c - ylo) * TSTR; s.t1 = (y1c - ylo) * TSTR;
    return s;
}

// sample 8 channels (half h) for one chunk-state from LDS tile / global fallback
__device__ __forceinline__ uint4v tap_sample(
    const TapS& s, int h, const unsigned int* __restrict__ tile,
    const float* __restrict__ sg)
{
    f32x2 sv[4];
    if (s.cond) {
#pragma unroll
        for (int wi = 0; wi < 4; ++wi) {
            const unsigned int* tw = tile + ((4 * h + wi) * TR) * TSTR;
            const unsigned int u00 = tw[s.t0 + s.x0c];
            const unsigned int u01 = tw[s.t0 + s.x1c];
            const unsigned int u10 = tw[s.t1 + s.x0c];
            const unsigned int u11 = tw[s.t1 + s.x1c];
            f32x2 c00, c01, c10, c11;
            c00[0] = __uint_as_float(u00 << 16); c00[1] = __uint_as_float(u00 & 0xFFFF0000u);
            c01[0] = __uint_as_float(u01 << 16); c01[1] = __uint_as_float(u01 & 0xFFFF0000u);
            c10[0] = __uint_as_float(u10 << 16); c10[1] = __uint_as_float(u10 & 0xFFFF0000u);
            c11[0] = __uint_as_float(u11 << 16); c11[1] = __uint_as_float(u11 & 0xFFFF0000u);
            sv[wi] = c00 * s.m0 + c01 * s.m1 + c10 * s.m2 + c11 * s.m3;
        }
    } else {
#pragma unroll
        for (int wi = 0; wi < 4; ++wi) {
            const float* sc0 = sg + (size_t)(8 * h + 2 * wi) * HW;
            const float* sc1 = sc0 + HW;
            sv[wi][0] = sc0[s.ia0] * s.m0 + sc0[s.ia1] * s.m1 + sc0[s.ia2] * s.m2 + sc0[s.ia3] * s.m3;
            sv[wi][1] = sc1[s.ia0] * s.m0 + sc1[s.ia1] * s.m1 + sc1[s.ia2] * s.m2 + sc1[s.ia3] * s.m3;
        }
    }
    uint4v bw;
#pragma unroll
    for (int wi = 0; wi < 4; ++wi) bw[wi] = pk2(sv[wi][0], sv[wi][1]);
    return bw;
}

// ---------- Kernel 2: deform conv — two chunks interleaved per tap ----------
// grid (Hn/ROWS, Bn*NG), 512 thr (8 waves). Wave wv: row r0+(wv>>1), chunks jb, jb+1.
__global__ __launch_bounds__(512, 4) void deform_kernel(
    const float* __restrict__ skip, const float* __restrict__ offs,
    const unsigned short* __restrict__ wA, float* __restrict__ out)
{
    __shared__ unsigned int tile[NW * TR * TSTR];   // 33792 B

    const int tid = threadIdx.x;
    const int g = blockIdx.y & 3;
    const int b = blockIdx.y >> 2;
    const int r0  = blockIdx.x * ROWS;
    const int ylo = max(0, r0 - 2);
    const int yhi = min(Hn - 1, r0 + ROWS + 1);

    const float* sg = skip + (size_t)(b * Cn + g * Cg) * HW;

    for (int i = tid; i < NW * TR * Wn; i += 512) {
        const int w  = i >> 10;
        const int re = i & 1023;
        const int ty = re >> 7;
        const int xx = re & 127;
        const int y  = ylo + ty;
        if (y <= yhi) {
            const float f0 = sg[(2 * w)     * HW + y * Wn + xx];
            const float f1 = sg[(2 * w + 1) * HW + y * Wn + xx];
            tile[(w * TR + ty) * TSTR + xx] = pk2(f0, f1);
        }
    }
    __syncthreads();

    const int wv   = tid >> 6;
    const int lane = tid & 63;
    const int p    = lane & 31;
    const int h    = lane >> 5;
    const int r    = r0 + (wv >> 1);
    const int jb   = (wv & 1) * 2;
    const int colA = jb * 32 + p;
    const int colB = colA + 32;

    const unsigned short* wAg = wA + (size_t)g * (KK * 512) + lane * 8;
    const float* offpA = offs + (size_t)b * OffC * HW + r * Wn + colA;
    const float* offpB = offpA + 32;

    f32x16 accA, accB;
#pragma unroll
    for (int i = 0; i < 16; ++i) { accA[i] = 0.f; accB[i] = 0.f; }

#pragma unroll 2
    for (int t = 0; t < KK; ++t) {
        const int ky = t / 3, kx = t % 3;
        // both chunks' offset loads issued together (4 independent)
        const float oyA = offpA[(2 * t) * HW];
        const float oxA = offpA[(2 * t + 1) * HW];
        const float oyB = offpB[(2 * t) * HW];
        const float oxB = offpB[(2 * t + 1) * HW];

        const TapS sA = tap_setup(r, colA, ky, kx, oyA, oxA, ylo, yhi);
        const TapS sB = tap_setup(r, colB, ky, kx, oyB, oxB, ylo, yhi);

        const uint4v bwA = tap_sample(sA, h, tile, sg);
        const uint4v bwB = tap_sample(sB, h, tile, sg);

        const short8v afrag = *(const short8v*)(wAg + t * 512);
        accA = __builtin_amdgcn_mfma_f32_32x32x16_bf16(afrag, __builtin_bit_cast(short8v, bwA), accA, 0, 0, 0);
        accB = __builtin_amdgcn_mfma_f32_32x32x16_bf16(afrag, __builtin_bit_cast(short8v, bwB), accB, 0, 0, 0);
    }

    float* obA = out + (size_t)(b * Cn + g * Cg) * HW + r * Wn + colA;
#pragma unroll
    for (int reg = 0; reg < 8; ++reg) {
        const int o = (reg & 3) + 8 * (reg >> 2) + 4 * h;
        obA[o * HW]      = accA[reg];
        obA[o * HW + 32] = accB[reg];
    }
}

extern "C" void kernel_launch(void* const* d_in, const int* in_sizes, int n_in,
                              void* d_out, int out_size, void* d_ws, size_t ws_size,
                              hipStream_t stream) {
    const float* x        = (const float*)d_in[0];
    const float* skip     = (const float*)d_in[1];
    const float* offset_w = (const float*)d_in[2];
    const float* offset_b = (const float*)d_in[3];
    const float* deform_w = (const float*)d_in[4];
    float* out  = (float*)d_out;

    float* offs = (float*)d_ws;                                   // 9.44 MB
    unsigned short* wAo = (unsigned short*)(offs + OFFS_ELEMS);   // 36.9 KB
    unsigned short* wAd = wAo + WAO_ELEMS;                        // 36.9 KB

    hipLaunchKernelGGL(prep_w_kernel, dim3(8), dim3(256), 0, stream,
                       offset_w, deform_w, wAo, wAd);
    hipLaunchKernelGGL(offset_conv_kernel, dim3(Hn, Bn), dim3(256), 0, stream,
                       x, wAo, offset_b, offs);
    hipLaunchKernelGGL(deform_kernel, dim3(Hn / ROWS, Bn * NG), dim3(512), 0, stream,
                       skip, offs, wAd, out);
}

// Round 13
// 84.191 us; speedup vs baseline: 1.2636x; 1.2636x over previous
//
#include <hip/hip_runtime.h>

#define Bn    8
#define Cn    64
#define Hn    128
#define Wn    128
#define KK    9
#define OffC  18
#define NG    4
#define Cg    16
#define HW    (Hn*Wn)

#define OFFS_ELEMS (Bn*OffC*HW)
#define WAO_ELEMS  (KK*4*64*8)
#define WAD_ELEMS  (NG*KK*64*8)

// deform tile geometry: 4 output rows, halo 2 up / 2 down (proven)
#define ROWS  4
#define TR    8
#define NW    8
#define TSTR  132

typedef __attribute__((ext_vector_type(8)))  short short8v;
typedef __attribute__((ext_vector_type(4)))  unsigned int uint4v;
typedef __attribute__((ext_vector_type(2)))  float f32x2;
typedef __attribute__((ext_vector_type(16))) float f32x16;

__device__ __forceinline__ unsigned int rne16(float f) {
    unsigned int u = __float_as_uint(f);
    return (u + 0x7FFFu + ((u >> 16) & 1u)) >> 16;   // bf16 RNE
}
// bf16 pair pack — PURE BIT MATH (compiler-schedulable; inline-asm cvt_pk was a
// 3x regression in the offset conv: m240 trap, verified round 12)
__device__ __forceinline__ unsigned int pack2(float lo, float hi) {
    const unsigned int a = rne16(lo);
    unsigned int b = __float_as_uint(hi);
    b = (b + 0x7FFFu + ((b >> 16) & 1u)) & 0xFFFF0000u;
    return b | a;
}

// ---------- Kernel 0: prep MFMA A-fragment tables (both convs) ----------
__global__ __launch_bounds__(256) void prep_w_kernel(
    const float* __restrict__ offw, const float* __restrict__ dw,
    unsigned short* __restrict__ wAo, unsigned short* __restrict__ wAd)
{
    const int tid = blockIdx.x * 256 + threadIdx.x;
    const int nth = gridDim.x * 256;
    for (int i = tid; i < WAO_ELEMS; i += nth) {
        const int e    = i & 7;
        const int lane = (i >> 3) & 63;
        const int q    = (i >> 9) & 3;
        const int t    = i >> 11;
        const int o    = lane & 31;
        const int c    = q * 16 + 8 * (lane >> 5) + e;
        const float v  = (o < OffC) ? offw[(o * Cn + c) * KK + t] : 0.f;
        wAo[i] = (unsigned short)rne16(v);
    }
    for (int i = tid; i < WAD_ELEMS; i += nth) {
        const int e    = i & 7;
        const int lane = (i >> 3) & 63;
        const int t    = (i >> 9) % KK;
        const int g    = i / (512 * KK);
        const int o    = lane & 31;
        const int c    = 8 * (lane >> 5) + e;
        const float v  = (o < Cg) ? dw[((g * Cg + o) * Cg + c) * KK + t] : 0.f;
        wAd[i] = (unsigned short)rne16(v);
    }
}

// ---------- Kernel 1: offset conv via MFMA (EXACT round-9 proven ~22 us version) ----------
__global__ __launch_bounds__(256, 4) void offset_conv_kernel(
    const float* __restrict__ x, const unsigned short* __restrict__ wAo,
    const float* __restrict__ bias, float* __restrict__ offs)
{
    const int tid  = threadIdx.x;
    const int wv   = tid >> 6;
    const int lane = tid & 63;
    const int p    = lane & 31;
    const int h    = lane >> 5;
    const int b    = blockIdx.y;
    const int r    = blockIdx.x;
    const int col  = wv * 32 + p;

    const float* xb = x + (size_t)b * Cn * HW;

    f32x16 acc;
#pragma unroll
    for (int i = 0; i < 16; ++i) acc[i] = 0.f;

#pragma unroll 1
    for (int q = 0; q < 4; ++q) {
        unsigned int win[4][3][3];
#pragma unroll
        for (int i = 0; i < 4; ++i) {
            const float* xc0 = xb + (size_t)(q * 16 + 8 * h + 2 * i) * HW;
            const float* xc1 = xc0 + HW;
#pragma unroll
            for (int ky = 0; ky < 3; ++ky) {
                const int  y   = r - 1 + ky;
                const bool yok = ((unsigned)y < (unsigned)Hn);
#pragma unroll
                for (int kx = 0; kx < 3; ++kx) {
                    const int  xx = col - 1 + kx;
                    const bool ok = yok && ((unsigned)xx < (unsigned)Wn);
                    const float f0 = ok ? xc0[y * Wn + xx] : 0.f;
                    const float f1 = ok ? xc1[y * Wn + xx] : 0.f;
                    win[i][ky][kx] = pack2(f0, f1);
                }
            }
        }
#pragma unroll
        for (int t = 0; t < KK; ++t) {
            uint4v bw;
            bw[0] = win[0][t / 3][t % 3];
            bw[1] = win[1][t / 3][t % 3];
            bw[2] = win[2][t / 3][t % 3];
            bw[3] = win[3][t / 3][t % 3];
            const short8v bfrag = __builtin_bit_cast(short8v, bw);
            const short8v afrag = *(const short8v*)(wAo + (size_t)(t * 4 + q) * 512 + lane * 8);
            acc = __builtin_amdgcn_mfma_f32_32x32x16_bf16(afrag, bfrag, acc, 0, 0, 0);
        }
    }

    float* ob = offs + ((size_t)b * OffC * Hn + r) * Wn + col;
#pragma unroll
    for (int reg = 0; reg < 16; ++reg) {
        const int o = (reg & 3) + 8 * (reg >> 2) + 4 * h;
        if (o < OffC) ob[(size_t)o * HW] = acc[reg] + bias[o];
    }
}

// ---------- helper: per-chunk tap state ----------
struct TapS {
    int   t0, t1;          // LDS row offsets (word units)
    int   ia0, ia1, ia2, ia3;
    float m0, m1, m2, m3;
    bool  cond;
    int   x0c, x1c;
};

__device__ __forceinline__ TapS tap_setup(
    int r, int col, int ky, int kx, float offy, float offx, int ylo, int yhi)
{
    TapS s;
    const float pyf = (float)(r - 1 + ky) + offy;
    const float pxf = (float)(col - 1 + kx) + offx;
    const float y0f = floorf(pyf), x0f = floorf(pxf);
    const float wy = pyf - y0f, wx = pxf - x0f;
    const int y0 = (int)y0f, x0 = (int)x0f, y1 = y0 + 1, x1 = x0 + 1;
    const bool vy0 = ((unsigned)y0 < (unsigned)Hn), vy1 = ((unsigned)y1 < (unsigned)Hn);
    const bool vx0 = ((unsigned)x0 < (unsigned)Wn), vx1 = ((unsigned)x1 < (unsigned)Wn);
    const int y0c = min(max(y0, 0), Hn - 1), y1c = min(max(y1, 0), Hn - 1);
    s.x0c = min(max(x0, 0), Wn - 1); s.x1c = min(max(x1, 0), Wn - 1);
    s.m0 = (1.f - wy) * (1.f - wx) * ((vy0 && vx0) ? 1.f : 0.f);
    s.m1 = (1.f - wy) * wx         * ((vy0 && vx1) ? 1.f : 0.f);
    s.m2 = wy * (1.f - wx)         * ((vy1 && vx0) ? 1.f : 0.f);
    s.m3 = wy * wx                 * ((vy1 && vx1) ? 1.f : 0.f);
    s.ia0 = y0c * Wn + s.x0c; s.ia1 = y0c * Wn + s.x1c;
    s.ia2 = y1c * Wn + s.x0c; s.ia3 = y1c * Wn + s.x1c;
    s.cond = (y0c >= ylo) && (y1c <= yhi);
    s.t0 = (y0c - ylo) * TSTR; s.t1 = (y1c - ylo) * TSTR;
    return s;
}

// sample 8 channels (half h) for one chunk-state from LDS tile / global fallback
__device__ __forceinline__ uint4v tap_sample(
    const TapS& s, int h, const unsigned int* __restrict__ tile,
    const float* __restrict__ sg)
{
    f32x2 sv[4];
    if (s.cond) {
#pragma unroll
        for (int wi = 0; wi < 4; ++wi) {
            const unsigned int* tw = tile + ((4 * h + wi) * TR) * TSTR;
            const unsigned int u00 = tw[s.t0 + s.x0c];
            const unsigned int u01 = tw[s.t0 + s.x1c];
            const unsigned int u10 = tw[s.t1 + s.x0c];
            const unsigned int u11 = tw[s.t1 + s.x1c];
            f32x2 c00, c01, c10, c11;
            c00[0] = __uint_as_float(u00 << 16); c00[1] = __uint_as_float(u00 & 0xFFFF0000u);
            c01[0] = __uint_as_float(u01 << 16); c01[1] = __uint_as_float(u01 & 0xFFFF0000u);
            c10[0] = __uint_as_float(u10 << 16); c10[1] = __uint_as_float(u10 & 0xFFFF0000u);
            c11[0] = __uint_as_float(u11 << 16); c11[1] = __uint_as_float(u11 & 0xFFFF0000u);
            sv[wi] = c00 * s.m0 + c01 * s.m1 + c10 * s.m2 + c11 * s.m3;   // v_pk_fma_f32
        }
    } else {
#pragma unroll
        for (int wi = 0; wi < 4; ++wi) {
            const float* sc0 = sg + (size_t)(8 * h + 2 * wi) * HW;
            const float* sc1 = sc0 + HW;
            sv[wi][0] = sc0[s.ia0] * s.m0 + sc0[s.ia1] * s.m1 + sc0[s.ia2] * s.m2 + sc0[s.ia3] * s.m3;
            sv[wi][1] = sc1[s.ia0] * s.m0 + sc1[s.ia1] * s.m1 + sc1[s.ia2] * s.m2 + sc1[s.ia3] * s.m3;
        }
    }
    uint4v bw;
#pragma unroll
    for (int wi = 0; wi < 4; ++wi) bw[wi] = pack2(sv[wi][0], sv[wi][1]);
    return bw;
}

// ---------- Kernel 2: deform conv — two chunks interleaved per tap (round-12 win) ----------
__global__ __launch_bounds__(512, 4) void deform_kernel(
    const float* __restrict__ skip, const float* __restrict__ offs,
    const unsigned short* __restrict__ wA, float* __restrict__ out)
{
    __shared__ unsigned int tile[NW * TR * TSTR];   // 33792 B

    const int tid = threadIdx.x;
    const int g = blockIdx.y & 3;
    const int b = blockIdx.y >> 2;
    const int r0  = blockIdx.x * ROWS;
    const int ylo = max(0, r0 - 2);
    const int yhi = min(Hn - 1, r0 + ROWS + 1);

    const float* sg = skip + (size_t)(b * Cn + g * Cg) * HW;

    for (int i = tid; i < NW * TR * Wn; i += 512) {
        const int w  = i >> 10;
        const int re = i & 1023;
        const int ty = re >> 7;
        const int xx = re & 127;
        const int y  = ylo + ty;
        if (y <= yhi) {
            const float f0 = sg[(2 * w)     * HW + y * Wn + xx];
            const float f1 = sg[(2 * w + 1) * HW + y * Wn + xx];
            tile[(w * TR + ty) * TSTR + xx] = pack2(f0, f1);
        }
    }
    __syncthreads();

    const int wv   = tid >> 6;
    const int lane = tid & 63;
    const int p    = lane & 31;
    const int h    = lane >> 5;
    const int r    = r0 + (wv >> 1);
    const int jb   = (wv & 1) * 2;
    const int colA = jb * 32 + p;
    const int colB = colA + 32;

    const unsigned short* wAg = wA + (size_t)g * (KK * 512) + lane * 8;
    const float* offpA = offs + (size_t)b * OffC * HW + r * Wn + colA;
    const float* offpB = offpA + 32;

    f32x16 accA, accB;
#pragma unroll
    for (int i = 0; i < 16; ++i) { accA[i] = 0.f; accB[i] = 0.f; }

#pragma unroll 2
    for (int t = 0; t < KK; ++t) {
        const int ky = t / 3, kx = t % 3;
        const float oyA = offpA[(2 * t) * HW];
        const float oxA = offpA[(2 * t + 1) * HW];
        const float oyB = offpB[(2 * t) * HW];
        const float oxB = offpB[(2 * t + 1) * HW];

        const TapS sA = tap_setup(r, colA, ky, kx, oyA, oxA, ylo, yhi);
        const TapS sB = tap_setup(r, colB, ky, kx, oyB, oxB, ylo, yhi);

        const uint4v bwA = tap_sample(sA, h, tile, sg);
        const uint4v bwB = tap_sample(sB, h, tile, sg);

        const short8v afrag = *(const short8v*)(wAg + t * 512);
        accA = __builtin_amdgcn_mfma_f32_32x32x16_bf16(afrag, __builtin_bit_cast(short8v, bwA), accA, 0, 0, 0);
        accB = __builtin_amdgcn_mfma_f32_32x32x16_bf16(afrag, __builtin_bit_cast(short8v, bwB), accB, 0, 0, 0);
    }

    float* obA = out + (size_t)(b * Cn + g * Cg) * HW + r * Wn + colA;
#pragma unroll
    for (int reg = 0; reg < 8; ++reg) {
        const int o = (reg & 3) + 8 * (reg >> 2) + 4 * h;
        obA[o * HW]      = accA[reg];
        obA[o * HW + 32] = accB[reg];
    }
}

extern "C" void kernel_launch(void* const* d_in, const int* in_sizes, int n_in,
                              void* d_out, int out_size, void* d_ws, size_t ws_size,
                              hipStream_t stream) {
    const float* x        = (const float*)d_in[0];
    const float* skip     = (const float*)d_in[1];
    const float* offset_w = (const float*)d_in[2];
    const float* offset_b = (const float*)d_in[3];
    const float* deform_w = (const float*)d_in[4];
    float* out  = (float*)d_out;

    float* offs = (float*)d_ws;                                   // 9.44 MB
    unsigned short* wAo = (unsigned short*)(offs + OFFS_ELEMS);   // 36.9 KB
    unsigned short* wAd = wAo + WAO_ELEMS;                        // 36.9 KB

    hipLaunchKernelGGL(prep_w_kernel, dim3(8), dim3(256), 0, stream,
                       offset_w, deform_w, wAo, wAd);
    hipLaunchKernelGGL(offset_conv_kernel, dim3(Hn, Bn), dim3(256), 0, stream,
                       x, wAo, offset_b, offs);
    hipLaunchKernelGGL(deform_kernel, dim3(Hn / ROWS, Bn * NG), dim3(512), 0, stream,
                       skip, offs, wAd, out);
}

// Round 14
// 80.313 us; speedup vs baseline: 1.3246x; 1.0483x over previous
//
#include <hip/hip_runtime.h>

#define Bn    8
#define Cn    64
#define Hn    128
#define Wn    128
#define KK    9
#define OffC  18
#define NG    4
#define Cg    16
#define HW    (Hn*Wn)

#define OFFS_ELEMS (Bn*OffC*HW)
#define WAO_ELEMS  (KK*4*64*8)
#define WAD_ELEMS  (NG*KK*64*8)

// deform tile geometry: 4 output rows, halo 2 up / 2 down (proven)
#define ROWS  4
#define TR    8
#define NW    8
#define TSTR  132

typedef __attribute__((ext_vector_type(8)))  short short8v;
typedef __attribute__((ext_vector_type(4)))  unsigned int uint4v;
typedef __attribute__((ext_vector_type(2)))  float f32x2;
typedef __attribute__((ext_vector_type(16))) float f32x16;

__device__ __forceinline__ unsigned int rne16(float f) {
    unsigned int u = __float_as_uint(f);
    return (u + 0x7FFFu + ((u >> 16) & 1u)) >> 16;   // bf16 RNE
}
// bf16 pair pack, PURE BIT MATH — required in the GLOBAL-load kernel (offset conv):
// inline-asm cvt_pk there = 3x regression (R12, m240 trap: asm fences load batching)
__device__ __forceinline__ unsigned int pack2(float lo, float hi) {
    const unsigned int a = rne16(lo);
    unsigned int b = __float_as_uint(hi);
    b = (b + 0x7FFFu + ((b >> 16) & 1u)) & 0xFFFF0000u;
    return b | a;
}
// bf16 pair pack, single v_cvt_pk_bf16_f32 — required in the LDS-load kernel (deform):
// R12 A/B: deform 60 -> ~34 us with this (VALU op count dominates there, LDS latency
// tolerates the asm scheduling barrier)
__device__ __forceinline__ unsigned int pk2(float lo, float hi) {
    unsigned int w;
    asm("v_cvt_pk_bf16_f32 %0, %1, %2" : "=v"(w) : "v"(lo), "v"(hi));
    return w;
}

// ---------- Kernel 0: prep MFMA A-fragment tables (both convs) ----------
__global__ __launch_bounds__(256) void prep_w_kernel(
    const float* __restrict__ offw, const float* __restrict__ dw,
    unsigned short* __restrict__ wAo, unsigned short* __restrict__ wAd)
{
    const int tid = blockIdx.x * 256 + threadIdx.x;
    const int nth = gridDim.x * 256;
    for (int i = tid; i < WAO_ELEMS; i += nth) {
        const int e    = i & 7;
        const int lane = (i >> 3) & 63;
        const int q    = (i >> 9) & 3;
        const int t    = i >> 11;
        const int o    = lane & 31;
        const int c    = q * 16 + 8 * (lane >> 5) + e;
        const float v  = (o < OffC) ? offw[(o * Cn + c) * KK + t] : 0.f;
        wAo[i] = (unsigned short)rne16(v);
    }
    for (int i = tid; i < WAD_ELEMS; i += nth) {
        const int e    = i & 7;
        const int lane = (i >> 3) & 63;
        const int t    = (i >> 9) % KK;
        const int g    = i / (512 * KK);
        const int o    = lane & 31;
        const int c    = 8 * (lane >> 5) + e;
        const float v  = (o < Cg) ? dw[((g * Cg + o) * Cg + c) * KK + t] : 0.f;
        wAd[i] = (unsigned short)rne16(v);
    }
}

// ---------- Kernel 1: offset conv via MFMA (EXACT round-9 proven ~22 us version) ----------
__global__ __launch_bounds__(256, 4) void offset_conv_kernel(
    const float* __restrict__ x, const unsigned short* __restrict__ wAo,
    const float* __restrict__ bias, float* __restrict__ offs)
{
    const int tid  = threadIdx.x;
    const int wv   = tid >> 6;
    const int lane = tid & 63;
    const int p    = lane & 31;
    const int h    = lane >> 5;
    const int b    = blockIdx.y;
    const int r    = blockIdx.x;
    const int col  = wv * 32 + p;

    const float* xb = x + (size_t)b * Cn * HW;

    f32x16 acc;
#pragma unroll
    for (int i = 0; i < 16; ++i) acc[i] = 0.f;

#pragma unroll 1
    for (int q = 0; q < 4; ++q) {
        unsigned int win[4][3][3];
#pragma unroll
        for (int i = 0; i < 4; ++i) {
            const float* xc0 = xb + (size_t)(q * 16 + 8 * h + 2 * i) * HW;
            const float* xc1 = xc0 + HW;
#pragma unroll
            for (int ky = 0; ky < 3; ++ky) {
                const int  y   = r - 1 + ky;
                const bool yok = ((unsigned)y < (unsigned)Hn);
#pragma unroll
                for (int kx = 0; kx < 3; ++kx) {
                    const int  xx = col - 1 + kx;
                    const bool ok = yok && ((unsigned)xx < (unsigned)Wn);
                    const float f0 = ok ? xc0[y * Wn + xx] : 0.f;
                    const float f1 = ok ? xc1[y * Wn + xx] : 0.f;
                    win[i][ky][kx] = pack2(f0, f1);
                }
            }
        }
#pragma unroll
        for (int t = 0; t < KK; ++t) {
            uint4v bw;
            bw[0] = win[0][t / 3][t % 3];
            bw[1] = win[1][t / 3][t % 3];
            bw[2] = win[2][t / 3][t % 3];
            bw[3] = win[3][t / 3][t % 3];
            const short8v bfrag = __builtin_bit_cast(short8v, bw);
            const short8v afrag = *(const short8v*)(wAo + (size_t)(t * 4 + q) * 512 + lane * 8);
            acc = __builtin_amdgcn_mfma_f32_32x32x16_bf16(afrag, bfrag, acc, 0, 0, 0);
        }
    }

    float* ob = offs + ((size_t)b * OffC * Hn + r) * Wn + col;
#pragma unroll
    for (int reg = 0; reg < 16; ++reg) {
        const int o = (reg & 3) + 8 * (reg >> 2) + 4 * h;
        if (o < OffC) ob[(size_t)o * HW] = acc[reg] + bias[o];
    }
}

// ---------- helper: per-chunk tap state ----------
struct TapS {
    int   t0, t1;          // LDS row offsets (word units)
    int   ia0, ia1, ia2, ia3;
    float m0, m1, m2, m3;
    bool  cond;
    int   x0c, x1c;
};

__device__ __forceinline__ TapS tap_setup(
    int r, int col, int ky, int kx, float offy, float offx, int ylo, int yhi)
{
    TapS s;
    const float pyf = (float)(r - 1 + ky) + offy;
    const float pxf = (float)(col - 1 + kx) + offx;
    const float y0f = floorf(pyf), x0f = floorf(pxf);
    const float wy = pyf - y0f, wx = pxf - x0f;
    const int y0 = (int)y0f, x0 = (int)x0f, y1 = y0 + 1, x1 = x0 + 1;
    const bool vy0 = ((unsigned)y0 < (unsigned)Hn), vy1 = ((unsigned)y1 < (unsigned)Hn);
    const bool vx0 = ((unsigned)x0 < (unsigned)Wn), vx1 = ((unsigned)x1 < (unsigned)Wn);
    const int y0c = min(max(y0, 0), Hn - 1), y1c = min(max(y1, 0), Hn - 1);
    s.x0c = min(max(x0, 0), Wn - 1); s.x1c = min(max(x1, 0), Wn - 1);
    s.m0 = (1.f - wy) * (1.f - wx) * ((vy0 && vx0) ? 1.f : 0.f);
    s.m1 = (1.f - wy) * wx         * ((vy0 && vx1) ? 1.f : 0.f);
    s.m2 = wy * (1.f - wx)         * ((vy1 && vx0) ? 1.f : 0.f);
    s.m3 = wy * wx                 * ((vy1 && vx1) ? 1.f : 0.f);
    s.ia0 = y0c * Wn + s.x0c; s.ia1 = y0c * Wn + s.x1c;
    s.ia2 = y1c * Wn + s.x0c; s.ia3 = y1c * Wn + s.x1c;
    s.cond = (y0c >= ylo) && (y1c <= yhi);
    s.t0 = (y0c - ylo) * TSTR; s.t1 = (y1c - ylo) * TSTR;
    return s;
}

// sample 8 channels (half h) for one chunk-state from LDS tile / global fallback
__device__ __forceinline__ uint4v tap_sample(
    const TapS& s, int h, const unsigned int* __restrict__ tile,
    const float* __restrict__ sg)
{
    f32x2 sv[4];
    if (s.cond) {
#pragma unroll
        for (int wi = 0; wi < 4; ++wi) {
            const unsigned int* tw = tile + ((4 * h + wi) * TR) * TSTR;
            const unsigned int u00 = tw[s.t0 + s.x0c];
            const unsigned int u01 = tw[s.t0 + s.x1c];
            const unsigned int u10 = tw[s.t1 + s.x0c];
            const unsigned int u11 = tw[s.t1 + s.x1c];
            f32x2 c00, c01, c10, c11;
            c00[0] = __uint_as_float(u00 << 16); c00[1] = __uint_as_float(u00 & 0xFFFF0000u);
            c01[0] = __uint_as_float(u01 << 16); c01[1] = __uint_as_float(u01 & 0xFFFF0000u);
            c10[0] = __uint_as_float(u10 << 16); c10[1] = __uint_as_float(u10 & 0xFFFF0000u);
            c11[0] = __uint_as_float(u11 << 16); c11[1] = __uint_as_float(u11 & 0xFFFF0000u);
            sv[wi] = c00 * s.m0 + c01 * s.m1 + c10 * s.m2 + c11 * s.m3;   // v_pk_fma_f32
        }
    } else {
#pragma unroll
        for (int wi = 0; wi < 4; ++wi) {
            const float* sc0 = sg + (size_t)(8 * h + 2 * wi) * HW;
            const float* sc1 = sc0 + HW;
            sv[wi][0] = sc0[s.ia0] * s.m0 + sc0[s.ia1] * s.m1 + sc0[s.ia2] * s.m2 + sc0[s.ia3] * s.m3;
            sv[wi][1] = sc1[s.ia0] * s.m0 + sc1[s.ia1] * s.m1 + sc1[s.ia2] * s.m2 + sc1[s.ia3] * s.m3;
        }
    }
    uint4v bw;
#pragma unroll
    for (int wi = 0; wi < 4; ++wi) bw[wi] = pk2(sv[wi][0], sv[wi][1]);   // deform: asm pack
    return bw;
}

// ---------- Kernel 2: deform conv — two chunks interleaved per tap, pk2 packs ----------
__global__ __launch_bounds__(512, 4) void deform_kernel(
    const float* __restrict__ skip, const float* __restrict__ offs,
    const unsigned short* __restrict__ wA, float* __restrict__ out)
{
    __shared__ unsigned int tile[NW * TR * TSTR];   // 33792 B

    const int tid = threadIdx.x;
    const int g = blockIdx.y & 3;
    const int b = blockIdx.y >> 2;
    const int r0  = blockIdx.x * ROWS;
    const int ylo = max(0, r0 - 2);
    const int yhi = min(Hn - 1, r0 + ROWS + 1);

    const float* sg = skip + (size_t)(b * Cn + g * Cg) * HW;

    for (int i = tid; i < NW * TR * Wn; i += 512) {
        const int w  = i >> 10;
        const int re = i & 1023;
        const int ty = re >> 7;
        const int xx = re & 127;
        const int y  = ylo + ty;
        if (y <= yhi) {
            const float f0 = sg[(2 * w)     * HW + y * Wn + xx];
            const float f1 = sg[(2 * w + 1) * HW + y * Wn + xx];
            tile[(w * TR + ty) * TSTR + xx] = pk2(f0, f1);
        }
    }
    __syncthreads();

    const int wv   = tid >> 6;
    const int lane = tid & 63;
    const int p    = lane & 31;
    const int h    = lane >> 5;
    const int r    = r0 + (wv >> 1);
    const int jb   = (wv & 1) * 2;
    const int colA = jb * 32 + p;
    const int colB = colA + 32;

    const unsigned short* wAg = wA + (size_t)g * (KK * 512) + lane * 8;
    const float* offpA = offs + (size_t)b * OffC * HW + r * Wn + colA;
    const float* offpB = offpA + 32;

    f32x16 accA, accB;
#pragma unroll
    for (int i = 0; i < 16; ++i) { accA[i] = 0.f; accB[i] = 0.f; }

#pragma unroll 2
    for (int t = 0; t < KK; ++t) {
        const int ky = t / 3, kx = t % 3;
        const float oyA = offpA[(2 * t) * HW];
        const float oxA = offpA[(2 * t + 1) * HW];
        const float oyB = offpB[(2 * t) * HW];
        const float oxB = offpB[(2 * t + 1) * HW];

        const TapS sA = tap_setup(r, colA, ky, kx, oyA, oxA, ylo, yhi);
        const TapS sB = tap_setup(r, colB, ky, kx, oyB, oxB, ylo, yhi);

        const uint4v bwA = tap_sample(sA, h, tile, sg);
        const uint4v bwB = tap_sample(sB, h, tile, sg);

        const short8v afrag = *(const short8v*)(wAg + t * 512);
        accA = __builtin_amdgcn_mfma_f32_32x32x16_bf16(afrag, __builtin_bit_cast(short8v, bwA), accA, 0, 0, 0);
        accB = __builtin_amdgcn_mfma_f32_32x32x16_bf16(afrag, __builtin_bit_cast(short8v, bwB), accB, 0, 0, 0);
    }

    float* obA = out + (size_t)(b * Cn + g * Cg) * HW + r * Wn + colA;
#pragma unroll
    for (int reg = 0; reg < 8; ++reg) {
        const int o = (reg & 3) + 8 * (reg >> 2) + 4 * h;
        obA[o * HW]      = accA[reg];
        obA[o * HW + 32] = accB[reg];
    }
}

extern "C" void kernel_launch(void* const* d_in, const int* in_sizes, int n_in,
                              void* d_out, int out_size, void* d_ws, size_t ws_size,
                              hipStream_t stream) {
    const float* x        = (const float*)d_in[0];
    const float* skip     = (const float*)d_in[1];
    const float* offset_w = (const float*)d_in[2];
    const float* offset_b = (const float*)d_in[3];
    const float* deform_w = (const float*)d_in[4];
    float* out  = (float*)d_out;

    float* offs = (float*)d_ws;                                   // 9.44 MB
    unsigned short* wAo = (unsigned short*)(offs + OFFS_ELEMS);   // 36.9 KB
    unsigned short* wAd = wAo + WAO_ELEMS;                        // 36.9 KB

    hipLaunchKernelGGL(prep_w_kernel, dim3(8), dim3(256), 0, stream,
                       offset_w, deform_w, wAo, wAd);
    hipLaunchKernelGGL(offset_conv_kernel, dim3(Hn, Bn), dim3(256), 0, stream,
                       x, wAo, offset_b, offs);
    hipLaunchKernelGGL(deform_kernel, dim3(Hn / ROWS, Bn * NG), dim3(512), 0, stream,
                       skip, offs, wAd, out);
}